// Round 2
// baseline (421.891 us; speedup 1.0000x reference)
//
#include <hip/hip_runtime.h>

// out[b,s,e] = prod_{j<=e} cos(x[b,s,j])  -- cumprod of cos along last axis.
// x: f32[16, 8192, 512] -> 131072 rows of 512 floats (2 KiB each).
//
// One 64-lane wave per row. Coalesced layout: lane i owns float4 #i
// (elements 4i..4i+3, first half) and float4 #(64+i) (second half) --
// every global_load/store_dwordx4 is perfectly contiguous across the wave.
// Two-segment wave scan stitches the halves: excl2 = total(half1) * scan(half2).
// cos via __cosf (v_cos_f32 HW transcendental): x ~ N(0,1) so the hw-cos
// absolute error (~1e-6) is far below the 2e-2 threshold; products decay
// ~0.6^k so only early positions contribute absolute error.

#define ROW_LEN 512

__global__ __launch_bounds__(256) void cumprod_cos_kernel(
    const float* __restrict__ x, float* __restrict__ out, int nrows) {
    const int wave_in_block = threadIdx.x >> 6;
    const int lane          = threadIdx.x & 63;
    const int row = blockIdx.x * (blockDim.x >> 6) + wave_in_block;
    if (row >= nrows) return;

    const size_t row_base = (size_t)row * ROW_LEN;
    const float4* __restrict__ xin = reinterpret_cast<const float4*>(x + row_base);
    float4* __restrict__ op        = reinterpret_cast<float4*>(out + row_base);

    // Perfectly coalesced: lane i -> float4 i (half 1) and float4 64+i (half 2)
    float4 a = xin[lane];
    float4 b = xin[64 + lane];

    // Hardware cosine
    float ca0 = __cosf(a.x), ca1 = __cosf(a.y), ca2 = __cosf(a.z), ca3 = __cosf(a.w);
    float cb0 = __cosf(b.x), cb1 = __cosf(b.y), cb2 = __cosf(b.z), cb3 = __cosf(b.w);

    // Lane-local inclusive prefix products within each 4-chunk
    float q0 = ca0, q1 = q0 * ca1, q2 = q1 * ca2, q3 = q2 * ca3;
    float r0 = cb0, r1 = r0 * cb1, r2 = r1 * cb2, r3 = r2 * cb3;

    // Wave scan (product) of first-half chunk totals
    float sq = q3;
    #pragma unroll
    for (int off = 1; off < 64; off <<= 1) {
        float n = __shfl_up(sq, off, 64);
        sq *= (lane >= off) ? n : 1.0f;
    }
    float excl_q = __shfl_up(sq, 1, 64);
    if (lane == 0) excl_q = 1.0f;
    const float total_q = __shfl(sq, 63, 64);   // product of entire first half

    // Wave scan of second-half chunk totals
    float sr = r3;
    #pragma unroll
    for (int off = 1; off < 64; off <<= 1) {
        float n = __shfl_up(sr, off, 64);
        sr *= (lane >= off) ? n : 1.0f;
    }
    float excl_r = __shfl_up(sr, 1, 64);
    if (lane == 0) excl_r = 1.0f;
    excl_r *= total_q;                          // fold in first-half total

    float4 o0 = make_float4(excl_q * q0, excl_q * q1, excl_q * q2, excl_q * q3);
    float4 o1 = make_float4(excl_r * r0, excl_r * r1, excl_r * r2, excl_r * r3);
    op[lane]      = o0;   // coalesced store, first half
    op[64 + lane] = o1;   // coalesced store, second half
}

extern "C" void kernel_launch(void* const* d_in, const int* in_sizes, int n_in,
                              void* d_out, int out_size, void* d_ws, size_t ws_size,
                              hipStream_t stream) {
    const float* x = (const float*)d_in[0];
    float* out = (float*)d_out;
    const int nrows = in_sizes[0] / ROW_LEN;  // 131072
    const int waves_per_block = 4;            // 256 threads
    const int grid = (nrows + waves_per_block - 1) / waves_per_block;
    cumprod_cos_kernel<<<grid, 256, 0, stream>>>(x, out, nrows);
}